// Round 1
// baseline (656.707 us; speedup 1.0000x reference)
//
#include <hip/hip_runtime.h>
#include <math.h>

#define N_ 32
#define D_ 512
#define S_ 1600
#define K_ 64

// ---------------------------------------------------------------------------
// Kernel A: fused per-pixel L2-norm + 1x1 conv (logits) + softmax.
//   outputs: aprime[n][k][s] = softmax_k * invnorm(n,s)   (so agg can use raw x)
//            asum[n][k]     += softmax_k                  (atomic, zeroed first)
// grid: N_ * (S_/64) = 800 blocks of 64 threads (1 wave). thread = one pixel.
// ---------------------------------------------------------------------------
__global__ __launch_bounds__(64) void kA(const float* __restrict__ x,
                                         const float* __restrict__ w,
                                         float* __restrict__ aprime,
                                         float* __restrict__ asum)
{
    __shared__ float wT[64 * 66];   // [dci][k], row stride 66: staging writes 2-way (free)
    const int tid = threadIdx.x;
    const int blk = blockIdx.x;
    const int n = blk / 25;
    const int s = (blk % 25) * 64 + tid;

    const float* xb = x + (size_t)n * D_ * S_ + s;

    float acc[K_];
#pragma unroll
    for (int k = 0; k < K_; ++k) acc[k] = 0.f;
    float ss = 0.f;

    for (int dc = 0; dc < D_; dc += 64) {
        __syncthreads();
        // stage w[k][dc+dci] -> wT[dci*66 + k]; iter j: k=j, dci=tid (coalesced)
#pragma unroll
        for (int j = 0; j < 64; ++j) {
            wT[tid * 66 + j] = w[j * D_ + dc + tid];
        }
        __syncthreads();

#pragma unroll 4
        for (int dci = 0; dci < 64; ++dci) {
            float xv = xb[(size_t)(dc + dci) * S_];
            ss += xv * xv;
            const float2* wr = (const float2*)&wT[dci * 66];
#pragma unroll
            for (int k2 = 0; k2 < 32; ++k2) {
                float2 wv = wr[k2];           // wave-uniform broadcast read
                acc[2 * k2]     += wv.x * xv;
                acc[2 * k2 + 1] += wv.y * xv;
            }
        }
    }

    const float inv = 1.0f / fmaxf(sqrtf(ss), 1e-12f);

    // stable softmax over k of (acc[k]*inv); inv>0 so max commutes with scale
    float m = -1e30f;
#pragma unroll
    for (int k = 0; k < K_; ++k) m = fmaxf(m, acc[k]);
    float sum = 0.f;
#pragma unroll
    for (int k = 0; k < K_; ++k) {
        acc[k] = __expf((acc[k] - m) * inv);
        sum += acc[k];
    }
    const float rs = 1.0f / sum;

    float* apb = aprime + (size_t)n * K_ * S_ + s;
#pragma unroll
    for (int k = 0; k < K_; ++k) {
        float a = acc[k] * rs;
        apb[(size_t)k * S_] = a * inv;   // coalesced over lanes
        // wave-reduce a across the 64 lanes, lane0 does one atomic
        float v = a;
        v += __shfl_xor(v, 32);
        v += __shfl_xor(v, 16);
        v += __shfl_xor(v, 8);
        v += __shfl_xor(v, 4);
        v += __shfl_xor(v, 2);
        v += __shfl_xor(v, 1);
        if (tid == 0) atomicAdd(&asum[n * K_ + k], v);
    }
}

// ---------------------------------------------------------------------------
// Kernel B: agg[n][k][d] = sum_s aprime[n][k][s] * x[n][d][s]
// grid: 32 n * 8 d-tiles = 256 blocks of 256 threads; 64k x 64d tile, 4x4 micro.
// ---------------------------------------------------------------------------
__global__ __launch_bounds__(256) void kB(const float* __restrict__ x,
                                          const float* __restrict__ aprime,
                                          float* __restrict__ agg)
{
    __shared__ float la[64 * 68];   // [sc][k], stride 68 (16B-aligned rows)
    __shared__ float lx[64 * 68];   // [sc][dd]
    const int tid = threadIdx.x;
    const int n  = blockIdx.x >> 3;
    const int d0 = (blockIdx.x & 7) * 64;
    const int lane_k = (tid & 15) * 4;
    const int lane_d = (tid >> 4) * 4;

    float acc[4][4];
#pragma unroll
    for (int i = 0; i < 4; ++i)
#pragma unroll
        for (int j = 0; j < 4; ++j) acc[i][j] = 0.f;

    const float* apb = aprime + (size_t)n * K_ * S_;
    const float* xb  = x + (size_t)n * D_ * S_ + (size_t)d0 * S_;

    for (int s0 = 0; s0 < S_; s0 += 64) {
        __syncthreads();
#pragma unroll
        for (int j = 0; j < 16; ++j) {
            int i   = tid + j * 256;
            int row = i >> 6;        // k (for la) / dd (for lx)
            int sc  = i & 63;        // = lane
            la[sc * 68 + row] = apb[(size_t)row * S_ + s0 + sc];
            lx[sc * 68 + row] = xb[(size_t)row * S_ + s0 + sc];
        }
        __syncthreads();

#pragma unroll 4
        for (int sc = 0; sc < 64; ++sc) {
            float4 av = *(const float4*)&la[sc * 68 + lane_k];
            float4 xv = *(const float4*)&lx[sc * 68 + lane_d];
            float a4[4] = {av.x, av.y, av.z, av.w};
            float x4[4] = {xv.x, xv.y, xv.z, xv.w};
#pragma unroll
            for (int i = 0; i < 4; ++i)
#pragma unroll
                for (int j = 0; j < 4; ++j) acc[i][j] += a4[i] * x4[j];
        }
    }

    float* ab = agg + (size_t)n * K_ * D_;
#pragma unroll
    for (int i = 0; i < 4; ++i) {
        float4 st = {acc[i][0], acc[i][1], acc[i][2], acc[i][3]};
        *(float4*)&ab[(size_t)(lane_k + i) * D_ + d0 + lane_d] = st;
    }
}

// ---------------------------------------------------------------------------
// Kernel C: vlad = agg - asum*centroid; intra-L2-norm over d; global norm = /8
// (post intra-norm every row has unit norm -> global L2 = sqrt(K) = 8 exactly)
// grid: N_*K_ = 2048 blocks of 256 threads; 2 elements/thread.
// ---------------------------------------------------------------------------
__global__ __launch_bounds__(256) void kC(const float* __restrict__ agg,
                                          const float* __restrict__ asum,
                                          const float* __restrict__ cent,
                                          float* __restrict__ out)
{
    __shared__ float red[4];
    const int tid = threadIdx.x;
    const int nk = blockIdx.x;
    const int k = nk & 63;
    const float as = asum[nk];
    const float* ag = agg + (size_t)nk * D_;
    const float* cb = cent + (size_t)k * D_;

    float v0 = ag[tid]       - as * cb[tid];
    float v1 = ag[tid + 256] - as * cb[tid + 256];
    float ss = v0 * v0 + v1 * v1;

    ss += __shfl_xor(ss, 32);
    ss += __shfl_xor(ss, 16);
    ss += __shfl_xor(ss, 8);
    ss += __shfl_xor(ss, 4);
    ss += __shfl_xor(ss, 2);
    ss += __shfl_xor(ss, 1);
    const int wave = tid >> 6;
    if ((tid & 63) == 0) red[wave] = ss;
    __syncthreads();
    const float total = red[0] + red[1] + red[2] + red[3];
    const float scale = 1.0f / (fmaxf(sqrtf(total), 1e-12f) * 8.0f);

    out[(size_t)nk * D_ + tid]       = v0 * scale;
    out[(size_t)nk * D_ + tid + 256] = v1 * scale;
}

// ---------------------------------------------------------------------------
extern "C" void kernel_launch(void* const* d_in, const int* in_sizes, int n_in,
                              void* d_out, int out_size, void* d_ws, size_t ws_size,
                              hipStream_t stream)
{
    const float* x    = (const float*)d_in[0];   // [32,512,40,40]
    const float* w    = (const float*)d_in[1];   // [64,512]
    const float* cent = (const float*)d_in[2];   // [64,512]
    float* out = (float*)d_out;                  // [32, 32768]

    float* aprime = (float*)d_ws;                         // N*K*S   = 3,276,800 f
    float* asum   = aprime + (size_t)N_ * K_ * S_;        // N*K     = 2,048 f
    float* agg    = asum + (size_t)N_ * K_;               // N*K*D   = 1,048,576 f

    hipMemsetAsync(asum, 0, (size_t)N_ * K_ * sizeof(float), stream);

    kA<<<N_ * (S_ / 64), 64, 0, stream>>>(x, w, aprime, asum);
    kB<<<N_ * (D_ / 64), 256, 0, stream>>>(x, aprime, agg);
    kC<<<N_ * K_, 256, 0, stream>>>(agg, asum, cent, out);
}